// Round 4
// baseline (236.809 us; speedup 1.0000x reference)
//
#include <hip/hip_runtime.h>
#include <hip/hip_bf16.h>
#include <cstdint>

// MXFP4 fake-quant linear: out = qdq(A) @ qdq(W)^T + bias
// A: [M,K] fp32, W: [N,K] fp32, bias: [N] fp32, out: [M,N] fp32
//
// Native MX path, LDS-free "flatmm" GEMM:
//  - quant pass emits packed e2m1 in MFMA-fragment tile order:
//      tile (tm, tk) = rows tm*16..+15, k tk*128..+127  -> 1024 B;
//      lane l = (kchunk<<4)|row holds its 16-B fragment at tile_base + l*16.
//    scales: per 4-tk group, lane l's 4 e8m0 bytes at group_base + l*4 + (tk&3).
//  - GEMM: perfectly coalesced global_load_dwordx4 per fragment, no LDS,
//    no barriers -> compiler pipelines with fine-grained vmcnt (AITER-style).
//  - v_mfma_scale_f32_16x16x128_f8f6f4 (fp4): layout/scale semantics verified
//    in R3 (absmax 0.0).

typedef float floatx4 __attribute__((ext_vector_type(4)));
typedef int intx8 __attribute__((ext_vector_type(8)));

// ---------------- quantize fp32 -> fragment-ordered fp4 + e8m0 scales -------

__device__ __forceinline__ int enc1(float x, float inv) {
    float q = x * inv;                         // inv = 2^-(e-2), exact
    q = fminf(fmaxf(q, -6.0f), 6.0f);
    int s = (int)(__float_as_uint(q) >> 31) << 3;
    float aq = fabsf(q);
    float ilsb = aq < 2.0f ? 2.0f : (aq < 4.0f ? 1.0f : 0.5f);
    float lsb  = aq < 2.0f ? 0.5f : (aq < 4.0f ? 1.0f : 2.0f);
    float ar = rintf(aq * ilsb) * lsb;         // RNE onto e2m1 grid (symmetric)
    int c;
    if (ar < 2.0f)      c = (int)(ar * 2.0f);     // 0,.5,1,1.5 -> 0..3
    else if (ar < 4.0f) c = 2 + (int)ar;          // 2,3 -> 4,5
    else                c = 4 + (int)(ar * 0.5f); // 4,6 -> 6,7
    return c | s;
}

// One thread per float4 (4 consecutive k); 8 consecutive lanes share a 1x32 block.
__global__ void quant_mxfp4_v4(const float* __restrict__ A, uint8_t* __restrict__ Aq,
                               uint8_t* __restrict__ Asc,
                               const float* __restrict__ W, uint8_t* __restrict__ Wq,
                               uint8_t* __restrict__ Wsc,
                               long na4, long ntot4, int k4shift, int K) {
    long t = (long)blockIdx.x * 256 + threadIdx.x;
    if (t >= ntot4) return;
    const float* src; uint8_t* dq; uint8_t* ds; long idx;
    if (t < na4) { src = A; dq = Aq; ds = Asc; idx = t; }
    else         { src = W; dq = Wq; ds = Wsc; idx = t - na4; }

    float4 f = ((const float4*)src)[idx];
    float amax = fmaxf(fmaxf(fabsf(f.x), fabsf(f.y)),
                       fmaxf(fabsf(f.z), fabsf(f.w)));
    amax = fmaxf(amax, __shfl_xor(amax, 1));
    amax = fmaxf(amax, __shfl_xor(amax, 2));
    amax = fmaxf(amax, __shfl_xor(amax, 4));

    int ebits = (int)((__float_as_uint(amax) >> 23) & 0xff);
    int sb;
    float inv;
    if (amax > 0.0f) {
        sb = ebits - 2; if (sb < 0) sb = 0;
        inv = __uint_as_float((unsigned)((256 - ebits) & 255) << 23); // 2^(2-e)
    } else {
        sb = 127;
        inv = 0.0f;
    }

    int c0 = enc1(f.x, inv), c1 = enc1(f.y, inv);
    int c2 = enc1(f.z, inv), c3 = enc1(f.w, inv);
    unsigned short pk =
        (unsigned short)(c0 | (c1 << 4) | (c2 << 8) | (c3 << 12));

    // destination mapping (fragment-tile order)
    int m = (int)(idx >> k4shift);            // row
    int k = (int)(idx & ((1 << k4shift) - 1)) << 2;
    int KT = K >> 7;                           // tiles along k
    int tm = m >> 4, tk = k >> 7;
    int lane = (((k >> 5) & 3) << 4) | (m & 15);
    size_t doff = (((size_t)tm * KT + tk) << 10) + (size_t)(lane << 4)
                + (size_t)(((k & 31) >> 2) << 1);
    *(unsigned short*)(dq + doff) = pk;

    if ((k & 31) == 0) {
        int KG = KT >> 2;
        size_t soff = (((size_t)tm * KG + (tk >> 2)) << 8)
                    + (size_t)(lane << 2) + (size_t)(tk & 3);
        ds[soff] = (uint8_t)sb;
    }
}

// ---------- LDS-free fp4 GEMM: C[M,N] = (Aq,As) x (Wq,Ws)^T + bias ----------
// A-frag (16x16x128): row = lane&15, k-chunk = lane>>4 (fragment = one 32-block)
// C/D: col = lane&15, row = (lane>>4)*4 + reg

__global__ void gemm_fp4_flat(const uint8_t* __restrict__ Aq, const uint8_t* __restrict__ Asc,
                              const uint8_t* __restrict__ Wq, const uint8_t* __restrict__ Wsc,
                              const float* __restrict__ bias, float* __restrict__ C,
                              int M, int N, int K) {
    const int tid = threadIdx.x;
    const int lane = tid & 63;
    const int w = tid >> 6;
    const int wr = w >> 1;
    const int wc = w & 1;
    const int row16 = lane & 15;
    const int quad = lane >> 4;
    const int m0 = blockIdx.y * 128;
    const int n0 = blockIdx.x * 128;
    const int KT = K >> 7;          // 16-B-chunk tiles along k (1024 B each)
    const int KG = KT >> 2;         // scale groups (4 tk per group)

    floatx4 acc[4][4];
#pragma unroll
    for (int i = 0; i < 4; i++)
#pragma unroll
        for (int j = 0; j < 4; j++) acc[i][j] = (floatx4){0.f, 0.f, 0.f, 0.f};

    const uint8_t* aP[4];
    const uint8_t* wP[4];
    const uint8_t* aS[4];
    const uint8_t* wS[4];
#pragma unroll
    for (int mi = 0; mi < 4; mi++) {
        int tm = (m0 >> 4) + wr * 4 + mi;
        aP[mi] = Aq + (((size_t)tm * KT) << 10) + (lane << 4);
        aS[mi] = Asc + (((size_t)tm * KG) << 8) + (lane << 2);
    }
#pragma unroll
    for (int ni = 0; ni < 4; ni++) {
        int tn = (n0 >> 4) + wc * 4 + ni;
        wP[ni] = Wq + (((size_t)tn * KT) << 10) + (lane << 4);
        wS[ni] = Wsc + (((size_t)tn * KG) << 8) + (lane << 2);
    }

    for (int g = 0; g < KG; ++g) {
        unsigned int sa32[4], sw32[4];
#pragma unroll
        for (int mi = 0; mi < 4; mi++)
            sa32[mi] = *(const unsigned int*)(aS[mi] + ((size_t)g << 8));
#pragma unroll
        for (int ni = 0; ni < 4; ni++)
            sw32[ni] = *(const unsigned int*)(wS[ni] + ((size_t)g << 8));

#pragma unroll
        for (int t = 0; t < 4; ++t) {
            int4 af[4], wf[4];
#pragma unroll
            for (int mi = 0; mi < 4; mi++)
                af[mi] = *(const int4*)(aP[mi] + ((size_t)(g * 4 + t) << 10));
#pragma unroll
            for (int ni = 0; ni < 4; ni++)
                wf[ni] = *(const int4*)(wP[ni] + ((size_t)(g * 4 + t) << 10));

#pragma unroll
            for (int mi = 0; mi < 4; mi++) {
                intx8 a8 = {af[mi].x, af[mi].y, af[mi].z, af[mi].w, 0, 0, 0, 0};
                int sa = (int)((sa32[mi] >> (t * 8)) & 0xff);
#pragma unroll
                for (int ni = 0; ni < 4; ni++) {
                    intx8 b8 = {wf[ni].x, wf[ni].y, wf[ni].z, wf[ni].w, 0, 0, 0, 0};
                    int sw = (int)((sw32[ni] >> (t * 8)) & 0xff);
                    acc[mi][ni] = __builtin_amdgcn_mfma_scale_f32_16x16x128_f8f6f4(
                        a8, b8, acc[mi][ni], 4, 4, 0, sa, 0, sw);
                }
            }
        }
    }

    // Epilogue: C/D layout col=lane&15, row=quad*4+reg
#pragma unroll
    for (int ni = 0; ni < 4; ni++) {
        int n = n0 + wc * 64 + ni * 16 + row16;
        float bv = bias[n];
#pragma unroll
        for (int mi = 0; mi < 4; mi++) {
            int mbase = m0 + wr * 64 + mi * 16 + quad * 4;
#pragma unroll
            for (int r = 0; r < 4; r++) {
                C[(size_t)(mbase + r) * N + n] = acc[mi][ni][r] + bv;
            }
        }
    }
}

// ---------------- launch ----------------

extern "C" void kernel_launch(void* const* d_in, const int* in_sizes, int n_in,
                              void* d_out, int out_size, void* d_ws, size_t ws_size,
                              hipStream_t stream) {
    const float* inp  = (const float*)d_in[0];
    const float* wgt  = (const float*)d_in[1];
    const float* bias = (const float*)d_in[2];
    float* out = (float*)d_out;

    const int N = in_sizes[2];                 // 2048
    const int K = in_sizes[1] / N;             // 2048
    const long M = (long)in_sizes[0] / K;      // 8192

    uint8_t* Aq4 = (uint8_t*)d_ws;             // M*K/2
    uint8_t* Wq4 = Aq4 + (size_t)M * K / 2;    // N*K/2
    uint8_t* Asc = Wq4 + (size_t)N * K / 2;    // M*K/32
    uint8_t* Wsc = Asc + (size_t)M * K / 32;   // N*K/32

    // K/4 is a power of two for this problem (K=2048)
    int k4 = K >> 2;
    int k4shift = 31 - __builtin_clz((unsigned)k4);

    long na4   = (long)M * K / 4;
    long ntot4 = na4 + (long)N * K / 4;
    quant_mxfp4_v4<<<dim3((ntot4 + 255) / 256), dim3(256), 0, stream>>>(
        inp, Aq4, Asc, wgt, Wq4, Wsc, na4, ntot4, k4shift, K);

    dim3 grid(N / 128, M / 128);
    gemm_fp4_flat<<<grid, dim3(256), 0, stream>>>(
        Aq4, Asc, Wq4, Wsc, bias, out, (int)M, N, K);
}

// Round 5
// 161.475 us; speedup vs baseline: 1.4665x; 1.4665x over previous
//
#include <hip/hip_runtime.h>
#include <hip/hip_bf16.h>
#include <cstdint>

// MXFP4 fake-quant linear: out = qdq(A) @ qdq(W)^T + bias
// A: [M,K] fp32, W: [N,K] fp32, bias: [N] fp32, out: [M,N] fp32
//
// Quant pass (verified R4, absmax 0.0): packed e2m1 in MFMA-fragment tile
// order: tile (tm,tk) = rows tm*16..+15 x k tk*128..+127 -> 1024 contiguous
// bytes, lane l = (kchunk<<4)|row owns bytes [l*16, l*16+16). Scales: per
// (tm, tg=tk>>2) 256-B chunk, lane l's 4 e8m0 bytes at lane*4 + (tk&3).
//
// GEMM: LDS double-buffered, raw s_barrier + manual s_waitcnt vmcnt(9)
// (m139-style) so next-iter global_load_lds stay in flight across the
// barrier. v_mfma_scale_f32_16x16x128_f8f6f4 fp4 (layout verified R3/R4).

typedef float floatx4 __attribute__((ext_vector_type(4)));
typedef int intx8 __attribute__((ext_vector_type(8)));

#define GLOBAL_AS __attribute__((address_space(1)))
#define LDS_AS __attribute__((address_space(3)))

// ---------------- quantize fp32 -> fragment-ordered fp4 + e8m0 scales -------

__device__ __forceinline__ int enc1(float x, float inv) {
    float q = x * inv;                         // inv = 2^-(e-2), exact
    q = fminf(fmaxf(q, -6.0f), 6.0f);
    int s = (int)(__float_as_uint(q) >> 31) << 3;
    float aq = fabsf(q);
    float ilsb = aq < 2.0f ? 2.0f : (aq < 4.0f ? 1.0f : 0.5f);
    float lsb  = aq < 2.0f ? 0.5f : (aq < 4.0f ? 1.0f : 2.0f);
    float ar = rintf(aq * ilsb) * lsb;         // RNE onto e2m1 grid (symmetric)
    int c;
    if (ar < 2.0f)      c = (int)(ar * 2.0f);     // 0,.5,1,1.5 -> 0..3
    else if (ar < 4.0f) c = 2 + (int)ar;          // 2,3 -> 4,5
    else                c = 4 + (int)(ar * 0.5f); // 4,6 -> 6,7
    return c | s;
}

__global__ void quant_mxfp4_v4(const float* __restrict__ A, uint8_t* __restrict__ Aq,
                               uint8_t* __restrict__ Asc,
                               const float* __restrict__ W, uint8_t* __restrict__ Wq,
                               uint8_t* __restrict__ Wsc,
                               long na4, long ntot4, int k4shift, int K) {
    long t = (long)blockIdx.x * 256 + threadIdx.x;
    if (t >= ntot4) return;
    const float* src; uint8_t* dq; uint8_t* ds; long idx;
    if (t < na4) { src = A; dq = Aq; ds = Asc; idx = t; }
    else         { src = W; dq = Wq; ds = Wsc; idx = t - na4; }

    float4 f = ((const float4*)src)[idx];
    float amax = fmaxf(fmaxf(fabsf(f.x), fabsf(f.y)),
                       fmaxf(fabsf(f.z), fabsf(f.w)));
    amax = fmaxf(amax, __shfl_xor(amax, 1));
    amax = fmaxf(amax, __shfl_xor(amax, 2));
    amax = fmaxf(amax, __shfl_xor(amax, 4));

    int ebits = (int)((__float_as_uint(amax) >> 23) & 0xff);
    int sb;
    float inv;
    if (amax > 0.0f) {
        sb = ebits - 2; if (sb < 0) sb = 0;
        inv = __uint_as_float((unsigned)((256 - ebits) & 255) << 23); // 2^(2-e)
    } else {
        sb = 127;
        inv = 0.0f;
    }

    int c0 = enc1(f.x, inv), c1 = enc1(f.y, inv);
    int c2 = enc1(f.z, inv), c3 = enc1(f.w, inv);
    unsigned short pk =
        (unsigned short)(c0 | (c1 << 4) | (c2 << 8) | (c3 << 12));

    int m = (int)(idx >> k4shift);
    int k = (int)(idx & ((1 << k4shift) - 1)) << 2;
    int KT = K >> 7;
    int tm = m >> 4, tk = k >> 7;
    int lane = (((k >> 5) & 3) << 4) | (m & 15);
    size_t doff = (((size_t)tm * KT + tk) << 10) + (size_t)(lane << 4)
                + (size_t)(((k & 31) >> 2) << 1);
    *(unsigned short*)(dq + doff) = pk;

    if ((k & 31) == 0) {
        int KG = KT >> 2;
        size_t soff = (((size_t)tm * KG + (tk >> 2)) << 8)
                    + (size_t)(lane << 2) + (size_t)(tk & 3);
        ds[soff] = (uint8_t)sb;
    }
}

// ---------- LDS-dbuf fp4 GEMM: C[M,N] = (Aq,As) x (Wq,Ws)^T + bias ----------
// Per iter g (256 k): stage 16 A-tiles + 16 W-tiles (1 KB each) + 4 KB scales.
// A-frag (16x16x128): row = lane&15, k-chunk = lane>>4.
// C/D: col = lane&15, row = (lane>>4)*4 + reg.

__global__ void gemm_fp4_dbuf(const uint8_t* __restrict__ Aq, const uint8_t* __restrict__ Asc,
                              const uint8_t* __restrict__ Wq, const uint8_t* __restrict__ Wsc,
                              const float* __restrict__ bias, float* __restrict__ C,
                              int M, int N, int K) {
    __shared__ __align__(16) uint8_t As4[2][16384];
    __shared__ __align__(16) uint8_t Ws4[2][16384];
    __shared__ __align__(16) uint8_t Ss[2][4096];

    const int tid = threadIdx.x;
    const int lane = tid & 63;
    const int w = tid >> 6;
    const int wr = w >> 1;
    const int wc = w & 1;
    const int row16 = lane & 15;
    const int quad = lane >> 4;
    const int m0 = blockIdx.y * 128;
    const int n0 = blockIdx.x * 128;
    const int KT = K >> 7;          // 1-KB fragment tiles along k
    const int KG = KT >> 2;         // scale groups (4 tk each)
    const int NIT = K >> 8;         // 256-k iterations

    floatx4 acc[4][4];
#pragma unroll
    for (int i = 0; i < 4; i++)
#pragma unroll
        for (int j = 0; j < 4; j++) acc[i][j] = (floatx4){0.f, 0.f, 0.f, 0.f};

    // stage one 256-k slab into buffer p: 9 global_load_lds per thread
    auto stage = [&](int g, int p) {
#pragma unroll
        for (int it = 0; it < 4; ++it) {
            int q = it * 256 + tid;
            int tIdx = q >> 6, chunk = q & 63;
            int tm = (m0 >> 4) + (tIdx >> 1);
            int tk = 2 * g + (tIdx & 1);
            const uint8_t* ga = Aq + (((size_t)tm * KT + tk) << 10) + (chunk << 4);
            __builtin_amdgcn_global_load_lds(
                (GLOBAL_AS void*)ga, (LDS_AS void*)(&As4[p][q * 16]), 16, 0, 0);
        }
#pragma unroll
        for (int it = 0; it < 4; ++it) {
            int q = it * 256 + tid;
            int tIdx = q >> 6, chunk = q & 63;
            int tn = (n0 >> 4) + (tIdx >> 1);
            int tk = 2 * g + (tIdx & 1);
            const uint8_t* gw = Wq + (((size_t)tn * KT + tk) << 10) + (chunk << 4);
            __builtin_amdgcn_global_load_lds(
                (GLOBAL_AS void*)gw, (LDS_AS void*)(&Ws4[p][q * 16]), 16, 0, 0);
        }
        {   // scales: 16 tiles x 256 B; tIdx<8 -> A (wave-uniform branch)
            int tIdx = tid >> 4, chunk = tid & 15;
            int tg = g >> 1;
            const uint8_t* gs;
            if (tIdx < 8) {
                int tm = (m0 >> 4) + tIdx;
                gs = Asc + (((size_t)tm * KG + tg) << 8) + (chunk << 4);
            } else {
                int tn = (n0 >> 4) + (tIdx - 8);
                gs = Wsc + (((size_t)tn * KG + tg) << 8) + (chunk << 4);
            }
            __builtin_amdgcn_global_load_lds(
                (GLOBAL_AS void*)gs, (LDS_AS void*)(&Ss[p][tid * 16]), 16, 0, 0);
        }
    };

    stage(0, 0);

    for (int g = 0; g < NIT; ++g) {
        int p = g & 1;
        // barrier A: everyone finished compute g-1 -> buffer p^1 reusable
        __builtin_amdgcn_s_barrier();
        if (g + 1 < NIT) {
            stage(g + 1, p ^ 1);
            // wait for the 9 stage-g loads (issued last iter); leave the 9
            // stage-(g+1) loads in flight across the barrier
            __builtin_amdgcn_s_waitcnt(0x0F79);   // vmcnt(9) lgkm/exp no-wait
        } else {
            __builtin_amdgcn_s_waitcnt(0x0F70);   // vmcnt(0)
        }
        // barrier B: stage-g data visible to all threads
        __builtin_amdgcn_s_barrier();

        unsigned sa32[4], sw32[4];
#pragma unroll
        for (int mi = 0; mi < 4; mi++)
            sa32[mi] = *(const unsigned*)(&Ss[p][((wr * 4 + mi) << 8) + (lane << 2)]);
#pragma unroll
        for (int ni = 0; ni < 4; ni++)
            sw32[ni] = *(const unsigned*)(&Ss[p][((8 + wc * 4 + ni) << 8) + (lane << 2)]);

        int bsel = (g & 1) * 2;
#pragma unroll
        for (int ks = 0; ks < 2; ++ks) {
            int4 af[4], wf[4];
#pragma unroll
            for (int mi = 0; mi < 4; mi++)
                af[mi] = *(const int4*)(&As4[p][((((wr * 4 + mi) << 1) | ks) << 10) + (lane << 4)]);
#pragma unroll
            for (int ni = 0; ni < 4; ni++)
                wf[ni] = *(const int4*)(&Ws4[p][((((wc * 4 + ni) << 1) | ks) << 10) + (lane << 4)]);

            int sh = 8 * (bsel + ks);
#pragma unroll
            for (int mi = 0; mi < 4; mi++) {
                intx8 a8 = {af[mi].x, af[mi].y, af[mi].z, af[mi].w, 0, 0, 0, 0};
                int sa = (int)((sa32[mi] >> sh) & 0xff);
#pragma unroll
                for (int ni = 0; ni < 4; ni++) {
                    intx8 b8 = {wf[ni].x, wf[ni].y, wf[ni].z, wf[ni].w, 0, 0, 0, 0};
                    int sw = (int)((sw32[ni] >> sh) & 0xff);
                    acc[mi][ni] = __builtin_amdgcn_mfma_scale_f32_16x16x128_f8f6f4(
                        a8, b8, acc[mi][ni], 4, 4, 0, sa, 0, sw);
                }
            }
        }
    }

    // Epilogue: C/D layout col=lane&15, row=quad*4+reg
#pragma unroll
    for (int ni = 0; ni < 4; ni++) {
        int n = n0 + wc * 64 + ni * 16 + row16;
        float bv = bias[n];
#pragma unroll
        for (int mi = 0; mi < 4; mi++) {
            int mbase = m0 + wr * 64 + mi * 16 + quad * 4;
#pragma unroll
            for (int r = 0; r < 4; r++) {
                C[(size_t)(mbase + r) * N + n] = acc[mi][ni][r] + bv;
            }
        }
    }
}

// ---------------- launch ----------------

extern "C" void kernel_launch(void* const* d_in, const int* in_sizes, int n_in,
                              void* d_out, int out_size, void* d_ws, size_t ws_size,
                              hipStream_t stream) {
    const float* inp  = (const float*)d_in[0];
    const float* wgt  = (const float*)d_in[1];
    const float* bias = (const float*)d_in[2];
    float* out = (float*)d_out;

    const int N = in_sizes[2];                 // 2048
    const int K = in_sizes[1] / N;             // 2048
    const long M = (long)in_sizes[0] / K;      // 8192

    uint8_t* Aq4 = (uint8_t*)d_ws;             // M*K/2
    uint8_t* Wq4 = Aq4 + (size_t)M * K / 2;    // N*K/2
    uint8_t* Asc = Wq4 + (size_t)N * K / 2;    // M*K/32
    uint8_t* Wsc = Asc + (size_t)M * K / 32;   // N*K/32

    int k4 = K >> 2;                           // K/4 (power of two here)
    int k4shift = 31 - __builtin_clz((unsigned)k4);

    long na4   = (long)M * K / 4;
    long ntot4 = na4 + (long)N * K / 4;
    quant_mxfp4_v4<<<dim3((ntot4 + 255) / 256), dim3(256), 0, stream>>>(
        inp, Aq4, Asc, wgt, Wq4, Wsc, na4, ntot4, k4shift, K);

    dim3 grid(N / 128, M / 128);
    gemm_fp4_dbuf<<<grid, dim3(256), 0, stream>>>(
        Aq4, Asc, Wq4, Wsc, bias, out, (int)M, N, K);
}